// Round 10
// baseline (868.329 us; speedup 1.0000x reference)
//
#include <hip/hip_runtime.h>

#define TLEN  1024
#define HN    64
#define LOG2E 1.4426950408889634f

// clang builtins use __fp16 vectors, NOT _Float16.
typedef __fp16 half2v __attribute__((ext_vector_type(2)));
typedef __fp16 half8v __attribute__((ext_vector_type(8)));
typedef float  float4v __attribute__((ext_vector_type(4)));

// One wave (64 lanes) per batch element, 1024 blocks (grid unchanged vs R3).
// R9 post-mortem: 2-wave split regressed (697 vs 524us) -- barrier/step
// serialized the waves and duplicated activations. R3's floor is the VALU
// issue path: 128 hh-fdot2 (~544cy) + 32 readlanes (~272cy). This version
// moves the hh matvec to the MATRIX pipe:
//   gates[256] = W_hh.h  ==  16 row-tiles x 2 K-halves of
//   v_mfma_f32_16x16x32_f16 with B's 16 columns ALL = h (replicated).
// De-risking after the R4-R6 layout failures:
//  * k-slot mapping CANCELS: dot products are permutation-invariant, so A
//    and B only need the SAME k indexing formula (k = (l>>4)*8 + j per
//    32-half). The HW's real k order is irrelevant.
//  * B col mapping irrelevant (columns identical). D layout is HW-VERIFIED
//    (learn_hip m89: col=lane&15, row=(lane>>4)*4+reg).
//  * Only unverified bit: A's m = lane&15 (standard documented layout).
//    Wrong => huge absmax, clear signal, fix = swap mfma operands.
// D-extraction without runtime reg indexing (rule #20): 16 unconditional
// ds_write_b128 dump each lane's D fragments into its OWN column-region of
// gbuf[16][264] (pad 8 dwords -> writes hit the 8-phase LDS floor, no extra
// conflict); all 16 regions end up identical full 256-row gate arrays; each
// lane then ds_read_b32 its unit's 4 gate rows {l,64+l,128+l,192+l} from
// region (l&15). Single wave => LDS ops in order, compiler inserts lgkm
// waits; no barriers in the recurrence.
// Activations / x-path / FC ring / x-staging: EXACTLY R3 (per-lane unit l,
// 8 x-fdot2 with pre-scaled weights+biases, log2e folded, 2*log2e for the
// tanh gate; h published to hbuf as f16 for next step's B rebuild).

#define FOR16(X) \
    X(0) X(1) X(2) X(3) X(4) X(5) X(6) X(7) \
    X(8) X(9) X(10) X(11) X(12) X(13) X(14) X(15)

__global__ __launch_bounds__(64, 1)
void lstm_mfma(const float* __restrict__ x,      // [B, T, 4]
               const float* __restrict__ W_ih,   // [256, 4]
               const float* __restrict__ W_hh,   // [256, 64]
               const float* __restrict__ b_ih,   // [256]
               const float* __restrict__ b_hh,   // [256]
               const float* __restrict__ W_fc,   // [1, 64]
               const float* __restrict__ b_fc,   // [1]
               float* __restrict__ out)          // [B, T]
{
    const int b   = blockIdx.x;
    const int l   = threadIdx.x;   // lane; also hidden unit for act/x/FC
    const int col = l & 15;        // A-row lane group / D col / region id
    const int rg  = l >> 4;        // k-group (A,B) / D row group

    __shared__ float ring[64][65];                    // FC partials
    __shared__ alignas(16) float gbuf[16][264];       // 16 gate regions, pad 8
    __shared__ alignas(16) unsigned short hbuf[HN];   // h_t as f16

    hbuf[l] = 0;   // h_0 = 0 (same wave writes & reads: in-order LDS)

    // ---- A fragments: 16 tiles x 2 K-halves, rows 16t+col, pre-scaled ----
#define DECLA(t) half8v a##t##_0, a##t##_1;
    FOR16(DECLA)
#undef DECLA

#define LOADA(t) { \
    const float sc = (((t) >> 2) == 2) ? (2.0f * LOG2E) : LOG2E; \
    const float* wr = W_hh + ((t) * 16 + col) * HN + rg * 8; \
    a##t##_0[0] = (__fp16)(wr[0] * sc);  a##t##_0[1] = (__fp16)(wr[1] * sc); \
    a##t##_0[2] = (__fp16)(wr[2] * sc);  a##t##_0[3] = (__fp16)(wr[3] * sc); \
    a##t##_0[4] = (__fp16)(wr[4] * sc);  a##t##_0[5] = (__fp16)(wr[5] * sc); \
    a##t##_0[6] = (__fp16)(wr[6] * sc);  a##t##_0[7] = (__fp16)(wr[7] * sc); \
    a##t##_1[0] = (__fp16)(wr[32] * sc); a##t##_1[1] = (__fp16)(wr[33] * sc); \
    a##t##_1[2] = (__fp16)(wr[34] * sc); a##t##_1[3] = (__fp16)(wr[35] * sc); \
    a##t##_1[4] = (__fp16)(wr[36] * sc); a##t##_1[5] = (__fp16)(wr[37] * sc); \
    a##t##_1[6] = (__fp16)(wr[38] * sc); a##t##_1[7] = (__fp16)(wr[39] * sc); \
    asm volatile("" : "+v"(a##t##_0), "+v"(a##t##_1)); }
    FOR16(LOADA)
#undef LOADA

    // ---- x-weights (unit l), pre-scaled; 2 half2 per gate (as R3) ----
    half2v wip0 = __builtin_amdgcn_cvt_pkrtz(W_ih[(0 * HN + l) * 4 + 0] * LOG2E,
                                             W_ih[(0 * HN + l) * 4 + 1] * LOG2E);
    half2v wip1 = __builtin_amdgcn_cvt_pkrtz(W_ih[(0 * HN + l) * 4 + 2] * LOG2E,
                                             W_ih[(0 * HN + l) * 4 + 3] * LOG2E);
    half2v wfp0 = __builtin_amdgcn_cvt_pkrtz(W_ih[(1 * HN + l) * 4 + 0] * LOG2E,
                                             W_ih[(1 * HN + l) * 4 + 1] * LOG2E);
    half2v wfp1 = __builtin_amdgcn_cvt_pkrtz(W_ih[(1 * HN + l) * 4 + 2] * LOG2E,
                                             W_ih[(1 * HN + l) * 4 + 3] * LOG2E);
    half2v wgp0 = __builtin_amdgcn_cvt_pkrtz(W_ih[(2 * HN + l) * 4 + 0] * 2.0f * LOG2E,
                                             W_ih[(2 * HN + l) * 4 + 1] * 2.0f * LOG2E);
    half2v wgp1 = __builtin_amdgcn_cvt_pkrtz(W_ih[(2 * HN + l) * 4 + 2] * 2.0f * LOG2E,
                                             W_ih[(2 * HN + l) * 4 + 3] * 2.0f * LOG2E);
    half2v wop0 = __builtin_amdgcn_cvt_pkrtz(W_ih[(3 * HN + l) * 4 + 0] * LOG2E,
                                             W_ih[(3 * HN + l) * 4 + 1] * LOG2E);
    half2v wop1 = __builtin_amdgcn_cvt_pkrtz(W_ih[(3 * HN + l) * 4 + 2] * LOG2E,
                                             W_ih[(3 * HN + l) * 4 + 3] * LOG2E);

    const float bias_i = (b_ih[0 * HN + l] + b_hh[0 * HN + l]) * LOG2E;
    const float bias_f = (b_ih[1 * HN + l] + b_hh[1 * HN + l]) * LOG2E;
    const float bias_g = (b_ih[2 * HN + l] + b_hh[2 * HN + l]) * (2.0f * LOG2E);
    const float bias_o = (b_ih[3 * HN + l] + b_hh[3 * HN + l]) * LOG2E;
    const float wfc = W_fc[l];
    const float bfc = b_fc[0];

    const float* xb = x   + (size_t)b * TLEN * 4;
    float*       ob = out + (size_t)b * TLEN;

    float h = 0.0f, c = 0.0f;
    const float4v zf = {0.0f, 0.0f, 0.0f, 0.0f};

    // ---- x stage: lane l holds x[t0 + l] (16B coalesced per chunk) ----
    float4 xcur = *(const float4*)(xb + (size_t)l * 4);   // chunk 0

    for (int ci = 0; ci < TLEN / 64; ++ci) {
        const int cn = (ci < TLEN / 64 - 1) ? ci + 1 : ci;
        float4 xnext = *(const float4*)(xb + (size_t)(cn * 64 + l) * 4);

        const int xq0 = __builtin_bit_cast(int, __builtin_amdgcn_cvt_pkrtz(xcur.x, xcur.y));
        const int xq1 = __builtin_bit_cast(int, __builtin_amdgcn_cvt_pkrtz(xcur.z, xcur.w));

        for (int s = 0; s < 64; ++s) {
            // ---- B fragments from hbuf (h_{t-1}); k = q*32 + rg*8 + j,
            //      SAME formula as A's gather => k order cancels ----
            const half8v b0 = *(const half8v*)&hbuf[rg * 8];
            const half8v b1 = *(const half8v*)&hbuf[32 + rg * 8];

            // ---- x broadcast + x-dot chains (independent of B: fills
            //      the B-read latency) ----
            const int xi0 = __builtin_amdgcn_readlane(xq0, s);
            const int xi1 = __builtin_amdgcn_readlane(xq1, s);
            const half2v xh0 = __builtin_bit_cast(half2v, xi0);
            const half2v xh1 = __builtin_bit_cast(half2v, xi1);

            float ai = __builtin_amdgcn_fdot2(wip0, xh0, bias_i, false);
            float af = __builtin_amdgcn_fdot2(wfp0, xh0, bias_f, false);
            float ag = __builtin_amdgcn_fdot2(wgp0, xh0, bias_g, false);
            float ao = __builtin_amdgcn_fdot2(wop0, xh0, bias_o, false);
            ai = __builtin_amdgcn_fdot2(wip1, xh1, ai, false);
            af = __builtin_amdgcn_fdot2(wfp1, xh1, af, false);
            ag = __builtin_amdgcn_fdot2(wgp1, xh1, ag, false);
            ao = __builtin_amdgcn_fdot2(wop1, xh1, ao, false);

            // ---- hh matvec on the matrix pipe: 16 tiles x 2 K-halves ----
#define MM(t) \
            float4v d##t = __builtin_amdgcn_mfma_f32_16x16x32_f16(a##t##_0, b0, zf, 0, 0, 0); \
            d##t = __builtin_amdgcn_mfma_f32_16x16x32_f16(a##t##_1, b1, d##t, 0, 0, 0);
            FOR16(MM)
#undef MM

            // ---- dump D: each lane writes its 4 rows of every tile into
            //      its own column-region (regions end up identical) ----
#define DUMP(t) *(float4v*)&gbuf[col][16 * (t) + rg * 4] = d##t;
            FOR16(DUMP)
#undef DUMP

            // ---- gather unit l's 4 gates (rows l, 64+l, 128+l, 192+l) ----
            ai += gbuf[col][l];
            af += gbuf[col][64 + l];
            ag += gbuf[col][128 + l];
            ao += gbuf[col][192 + l];

            // ---- activations (pre-scaled): sigmoid/tanh via exp2+rcp ----
            float si = __builtin_amdgcn_rcpf(1.0f + __builtin_amdgcn_exp2f(-ai));
            float sf = __builtin_amdgcn_rcpf(1.0f + __builtin_amdgcn_exp2f(-af));
            float tg = 1.0f - 2.0f * __builtin_amdgcn_rcpf(
                                         1.0f + __builtin_amdgcn_exp2f(ag));
            float so = __builtin_amdgcn_rcpf(1.0f + __builtin_amdgcn_exp2f(-ao));

            c = sf * c + si * tg;
            float th = 1.0f - 2.0f * __builtin_amdgcn_rcpf(
                           1.0f + __builtin_amdgcn_exp2f(c * (2.0f * LOG2E)));
            h = so * th;

            // ---- publish h (f16, RTZ as prior rounds) + FC partial ----
            const int hpk = __builtin_bit_cast(int,
                                __builtin_amdgcn_cvt_pkrtz(h, h));
            hbuf[l] = (unsigned short)(hpk & 0xffff);
            ring[s][l] = h * wfc;
        }

        // ---- FC: transposed reduce + coalesced 64-wide store ----
        __syncthreads();   // single wave: orders LDS w->r
        float s0 = 0.f, s1 = 0.f, s2 = 0.f, s3 = 0.f;
#pragma unroll
        for (int k = 0; k < HN; k += 4) {
            s0 += ring[l][k];
            s1 += ring[l][k + 1];
            s2 += ring[l][k + 2];
            s3 += ring[l][k + 3];
        }
        ob[ci * 64 + l] = (s0 + s1) + (s2 + s3) + bfc;

        xcur = xnext;
    }
}

extern "C" void kernel_launch(void* const* d_in, const int* in_sizes, int n_in,
                              void* d_out, int out_size, void* d_ws, size_t ws_size,
                              hipStream_t stream) {
    const float* x    = (const float*)d_in[0];
    const float* W_ih = (const float*)d_in[1];
    const float* W_hh = (const float*)d_in[2];
    const float* b_ih = (const float*)d_in[3];
    const float* b_hh = (const float*)d_in[4];
    const float* W_fc = (const float*)d_in[5];
    const float* b_fc = (const float*)d_in[6];
    float* out = (float*)d_out;

    const int B = in_sizes[0] / (TLEN * 4);   // 1024
    lstm_mfma<<<dim3(B), dim3(64), 0, stream>>>(
        x, W_ih, W_hh, b_ih, b_hh, W_fc, b_fc, out);
}

// Round 11
// 525.808 us; speedup vs baseline: 1.6514x; 1.6514x over previous
//
#include <hip/hip_runtime.h>

#define TLEN  1024
#define HN    64
#define LOG2E 1.4426950408889634f

// clang builtins use __fp16 vectors, NOT _Float16.
typedef __fp16 half2v __attribute__((ext_vector_type(2)));
typedef __fp16 half8v __attribute__((ext_vector_type(8)));
typedef float  float4v __attribute__((ext_vector_type(4)));

// One wave (64 lanes) per batch element, 1024 blocks. hh matvec on the
// MATRIX pipe, operand-flipped vs R10 so D needs NO LDS extraction:
//   D_t = A.B_t with A = h REPLICATED over the 16 M-rows (A-fragment is a
//   broadcast h k-slice: 2 uniform ds_read_b128), B_t = W_hh^T chunk
//   (lane holds W[t*16+col][k-slice], contiguous gather as R10).
//   => D_t[m][n] = gate (t*16+n), m-rows identical. Lane l (col=l&15,
//   rg=l>>4) holds gate t*16+col in EVERY acc reg of tile t. Lane l needs
//   gates G*64+l = tile G*4+rg, col l&15 = its own column -> selection
//   among 4 tiles by rg = 3 v_cndmask per gate, 12 VALU total.
//   NO dump, NO gather, NO bank conflicts (R10: 1.34e8 conflict-cycles +
//   lgkm round-trip = the 868us; MfmaUtil 26 / VALUBusy 17 = both pipes
//   waiting on LDS).
// Verified by R10's pass: A row mapping m=lane&15, k=(lane>>4)*8+j formula
// (cancels when A and B use the same one), D layout (m89). New assumption
// here: B col mapping n=lane&15 (standard; wrong => unit-permuted gates =
// huge absmax, unambiguous signal -> revert to R3 base).
// hbuf WAR is safe single-wave: reads (start of step) precede the write
// (end of step) in program order; compiler orders same-object LDS ops via
// lgkmcnt. No barriers in the recurrence.
// Carried EXACTLY from R3: x staged 64 steps/chunk (coalesced 16B/lane,
// 2 readlane broadcasts/step, 64-step prefetch), 8 x-fdot2 with pre-scaled
// f16 weights + biases (log2e folded, 2*log2e for tanh gate), exp2+rcp
// activations, FC ring[64][65] + epilogue outside the loop, h published as
// f16 RTZ (cvt_pkrtz low half).

#define FOR16(X) \
    X(0) X(1) X(2) X(3) X(4) X(5) X(6) X(7) \
    X(8) X(9) X(10) X(11) X(12) X(13) X(14) X(15)

__global__ __launch_bounds__(64, 1)
void lstm_mfma2(const float* __restrict__ x,      // [B, T, 4]
                const float* __restrict__ W_ih,   // [256, 4]
                const float* __restrict__ W_hh,   // [256, 64]
                const float* __restrict__ b_ih,   // [256]
                const float* __restrict__ b_hh,   // [256]
                const float* __restrict__ W_fc,   // [1, 64]
                const float* __restrict__ b_fc,   // [1]
                float* __restrict__ out)          // [B, T]
{
    const int b   = blockIdx.x;
    const int l   = threadIdx.x;   // lane; unit for act/x/FC
    const int col = l & 15;        // B col / D col
    const int rg  = l >> 4;        // k-group; D row-group (replicated rows)

    __shared__ float ring[64][65];                    // FC partials
    __shared__ alignas(16) unsigned short hbuf[HN];   // h_t as f16

    hbuf[l] = 0;   // h_0 = 0 (single wave: in-order LDS, no barrier)

    // ---- B fragments: 16 tiles x 2 K-halves, W rows as COLUMNS ----
    // wb_t_kh[j] = W_hh[t*16+col][kh*32 + rg*8 + j] * scale(t)
#define DECLW(t) half8v wb##t##_0, wb##t##_1;
    FOR16(DECLW)
#undef DECLW

#define LOADW(t) { \
    const float sc = (((t) >> 2) == 2) ? (2.0f * LOG2E) : LOG2E; \
    const float* wr = W_hh + ((t) * 16 + col) * HN + rg * 8; \
    wb##t##_0[0] = (__fp16)(wr[0] * sc);  wb##t##_0[1] = (__fp16)(wr[1] * sc); \
    wb##t##_0[2] = (__fp16)(wr[2] * sc);  wb##t##_0[3] = (__fp16)(wr[3] * sc); \
    wb##t##_0[4] = (__fp16)(wr[4] * sc);  wb##t##_0[5] = (__fp16)(wr[5] * sc); \
    wb##t##_0[6] = (__fp16)(wr[6] * sc);  wb##t##_0[7] = (__fp16)(wr[7] * sc); \
    wb##t##_1[0] = (__fp16)(wr[32] * sc); wb##t##_1[1] = (__fp16)(wr[33] * sc); \
    wb##t##_1[2] = (__fp16)(wr[34] * sc); wb##t##_1[3] = (__fp16)(wr[35] * sc); \
    wb##t##_1[4] = (__fp16)(wr[36] * sc); wb##t##_1[5] = (__fp16)(wr[37] * sc); \
    wb##t##_1[6] = (__fp16)(wr[38] * sc); wb##t##_1[7] = (__fp16)(wr[39] * sc); \
    asm volatile("" : "+v"(wb##t##_0), "+v"(wb##t##_1)); }
    FOR16(LOADW)
#undef LOADW

    // ---- x-weights (unit l), pre-scaled; 2 half2 per gate (as R3) ----
    half2v wip0 = __builtin_amdgcn_cvt_pkrtz(W_ih[(0 * HN + l) * 4 + 0] * LOG2E,
                                             W_ih[(0 * HN + l) * 4 + 1] * LOG2E);
    half2v wip1 = __builtin_amdgcn_cvt_pkrtz(W_ih[(0 * HN + l) * 4 + 2] * LOG2E,
                                             W_ih[(0 * HN + l) * 4 + 3] * LOG2E);
    half2v wfp0 = __builtin_amdgcn_cvt_pkrtz(W_ih[(1 * HN + l) * 4 + 0] * LOG2E,
                                             W_ih[(1 * HN + l) * 4 + 1] * LOG2E);
    half2v wfp1 = __builtin_amdgcn_cvt_pkrtz(W_ih[(1 * HN + l) * 4 + 2] * LOG2E,
                                             W_ih[(1 * HN + l) * 4 + 3] * LOG2E);
    half2v wgp0 = __builtin_amdgcn_cvt_pkrtz(W_ih[(2 * HN + l) * 4 + 0] * 2.0f * LOG2E,
                                             W_ih[(2 * HN + l) * 4 + 1] * 2.0f * LOG2E);
    half2v wgp1 = __builtin_amdgcn_cvt_pkrtz(W_ih[(2 * HN + l) * 4 + 2] * 2.0f * LOG2E,
                                             W_ih[(2 * HN + l) * 4 + 3] * 2.0f * LOG2E);
    half2v wop0 = __builtin_amdgcn_cvt_pkrtz(W_ih[(3 * HN + l) * 4 + 0] * LOG2E,
                                             W_ih[(3 * HN + l) * 4 + 1] * LOG2E);
    half2v wop1 = __builtin_amdgcn_cvt_pkrtz(W_ih[(3 * HN + l) * 4 + 2] * LOG2E,
                                             W_ih[(3 * HN + l) * 4 + 3] * LOG2E);

    const float bias_i = (b_ih[0 * HN + l] + b_hh[0 * HN + l]) * LOG2E;
    const float bias_f = (b_ih[1 * HN + l] + b_hh[1 * HN + l]) * LOG2E;
    const float bias_g = (b_ih[2 * HN + l] + b_hh[2 * HN + l]) * (2.0f * LOG2E);
    const float bias_o = (b_ih[3 * HN + l] + b_hh[3 * HN + l]) * LOG2E;
    const float wfc = W_fc[l];
    const float bfc = b_fc[0];

    const bool rb0 = (rg & 1) != 0;   // tile-select bits (divergent -> cndmask)
    const bool rb1 = (rg & 2) != 0;

    const float* xb = x   + (size_t)b * TLEN * 4;
    float*       ob = out + (size_t)b * TLEN;

    float h = 0.0f, c = 0.0f;
    const float4v zf = {0.0f, 0.0f, 0.0f, 0.0f};

    // ---- x stage: lane l holds x[t0 + l] (16B coalesced per chunk) ----
    float4 xcur = *(const float4*)(xb + (size_t)l * 4);   // chunk 0

    for (int ci = 0; ci < TLEN / 64; ++ci) {
        const int cn = (ci < TLEN / 64 - 1) ? ci + 1 : ci;
        float4 xnext = *(const float4*)(xb + (size_t)(cn * 64 + l) * 4);

        const int xq0 = __builtin_bit_cast(int, __builtin_amdgcn_cvt_pkrtz(xcur.x, xcur.y));
        const int xq1 = __builtin_bit_cast(int, __builtin_amdgcn_cvt_pkrtz(xcur.z, xcur.w));

        for (int s = 0; s < 64; ++s) {
            // ---- A fragments: broadcast h k-slices (2 uniform b128) ----
            const half8v a0 = *(const half8v*)&hbuf[rg * 8];
            const half8v a1 = *(const half8v*)&hbuf[32 + rg * 8];

            // ---- x broadcast + x-dot chains (fill the read latency) ----
            const int xi0 = __builtin_amdgcn_readlane(xq0, s);
            const int xi1 = __builtin_amdgcn_readlane(xq1, s);
            const half2v xh0 = __builtin_bit_cast(half2v, xi0);
            const half2v xh1 = __builtin_bit_cast(half2v, xi1);

            float ai = __builtin_amdgcn_fdot2(wip0, xh0, bias_i, false);
            float af = __builtin_amdgcn_fdot2(wfp0, xh0, bias_f, false);
            float ag = __builtin_amdgcn_fdot2(wgp0, xh0, bias_g, false);
            float ao = __builtin_amdgcn_fdot2(wop0, xh0, bias_o, false);
            ai = __builtin_amdgcn_fdot2(wip1, xh1, ai, false);
            af = __builtin_amdgcn_fdot2(wfp1, xh1, af, false);
            ag = __builtin_amdgcn_fdot2(wgp1, xh1, ag, false);
            ao = __builtin_amdgcn_fdot2(wop1, xh1, ao, false);

            // ---- hh matvec: 16 tiles x 2 K-halves, h as A (replicated) ----
#define MM(t) \
            float4v d##t = __builtin_amdgcn_mfma_f32_16x16x32_f16(a0, wb##t##_0, zf, 0, 0, 0); \
            d##t = __builtin_amdgcn_mfma_f32_16x16x32_f16(a1, wb##t##_1, d##t, 0, 0, 0);
            FOR16(MM)
#undef MM

            // ---- gate select: tile G*4+rg, own col; 3 cndmask/gate ----
            {
                const float i01 = rb0 ? d1[0]  : d0[0];
                const float i23 = rb0 ? d3[0]  : d2[0];
                ai += rb1 ? i23 : i01;
                const float f01 = rb0 ? d5[0]  : d4[0];
                const float f23 = rb0 ? d7[0]  : d6[0];
                af += rb1 ? f23 : f01;
                const float g01 = rb0 ? d9[0]  : d8[0];
                const float g23 = rb0 ? d11[0] : d10[0];
                ag += rb1 ? g23 : g01;
                const float o01 = rb0 ? d13[0] : d12[0];
                const float o23 = rb0 ? d15[0] : d14[0];
                ao += rb1 ? o23 : o01;
            }

            // ---- activations (pre-scaled): sigmoid/tanh via exp2+rcp ----
            float si = __builtin_amdgcn_rcpf(1.0f + __builtin_amdgcn_exp2f(-ai));
            float sf = __builtin_amdgcn_rcpf(1.0f + __builtin_amdgcn_exp2f(-af));
            float tg = 1.0f - 2.0f * __builtin_amdgcn_rcpf(
                                         1.0f + __builtin_amdgcn_exp2f(ag));
            float so = __builtin_amdgcn_rcpf(1.0f + __builtin_amdgcn_exp2f(-ao));

            c = sf * c + si * tg;
            float th = 1.0f - 2.0f * __builtin_amdgcn_rcpf(
                           1.0f + __builtin_amdgcn_exp2f(c * (2.0f * LOG2E)));
            h = so * th;

            // ---- publish h (f16 RTZ) + FC partial ----
            const int hpk = __builtin_bit_cast(int,
                                __builtin_amdgcn_cvt_pkrtz(h, h));
            hbuf[l] = (unsigned short)(hpk & 0xffff);
            ring[s][l] = h * wfc;
        }

        // ---- FC: transposed reduce + coalesced 64-wide store ----
        __syncthreads();   // single wave: orders LDS w->r
        float s0 = 0.f, s1 = 0.f, s2 = 0.f, s3 = 0.f;
#pragma unroll
        for (int k = 0; k < HN; k += 4) {
            s0 += ring[l][k];
            s1 += ring[l][k + 1];
            s2 += ring[l][k + 2];
            s3 += ring[l][k + 3];
        }
        ob[ci * 64 + l] = (s0 + s1) + (s2 + s3) + bfc;

        xcur = xnext;
    }
}

extern "C" void kernel_launch(void* const* d_in, const int* in_sizes, int n_in,
                              void* d_out, int out_size, void* d_ws, size_t ws_size,
                              hipStream_t stream) {
    const float* x    = (const float*)d_in[0];
    const float* W_ih = (const float*)d_in[1];
    const float* W_hh = (const float*)d_in[2];
    const float* b_ih = (const float*)d_in[3];
    const float* b_hh = (const float*)d_in[4];
    const float* W_fc = (const float*)d_in[5];
    const float* b_fc = (const float*)d_in[6];
    float* out = (float*)d_out;

    const int B = in_sizes[0] / (TLEN * 4);   // 1024
    lstm_mfma2<<<dim3(B), dim3(64), 0, stream>>>(
        x, W_ih, W_hh, b_ih, b_hh, W_fc, b_fc, out);
}